// Round 18
// baseline (543.166 us; speedup 1.0000x reference)
//
#include <hip/hip_runtime.h>
#include <hip/hip_fp16.h>

// GCN: 3x (h = X@W; agg = CSR-gather(norm_e * h[src]) + norm_self*h + b; relu)
// then mean-pool by graph id and a 128x8 linear head.
// R1: scatter->gather. R3: fp16 payload. R8: fp16 B + NT stores.
// R12: tail fold. R13: 8-lane gather_pool. R14: bs-counts. 510-512 us.
// R15 (reverted): bucket binning -> few-address atomic contention.
// R17: halve the csr scatter region: store only src (4B) and recompute
//      w = dinv[src]*dinv[dst] in the gathers (dinv = 400KB, L2-hit,
//      wave-broadcast). Random-scatter dirty-line count halves.

#define THREADS 256

// ---------------- degree(int) / dinv ----------------

__global__ __launch_bounds__(THREADS) void k_deg(const int* __restrict__ dst,
                                                 int* __restrict__ degi, int E) {
  int e = blockIdx.x * THREADS + threadIdx.x;
  if (e < E) atomicAdd(&degi[dst[e]], 1);
}

// counts via binary search over sorted batch (no atomics)
__global__ __launch_bounds__(THREADS) void k_cntbs(const int* __restrict__ batch,
                                                   float* __restrict__ cnts,
                                                   int N, int G) {
  int g = blockIdx.x * THREADS + threadIdx.x;
  if (g >= G) return;
  int lo = 0, hi = N;
  while (lo < hi) {
    int mid = (lo + hi) >> 1;
    if (batch[mid] < g) lo = mid + 1; else hi = mid;
  }
  int lb0 = lo;
  lo = 0; hi = N;
  while (lo < hi) {
    int mid = (lo + hi) >> 1;
    if (batch[mid] < g + 1) lo = mid + 1; else hi = mid;
  }
  cnts[g] = (float)(lo - lb0);
}

__global__ __launch_bounds__(THREADS) void k_rsq(const int* __restrict__ degi,
                                                 float* __restrict__ dinv, int N) {
  int i = blockIdx.x * THREADS + threadIdx.x;
  if (i < N) dinv[i] = rsqrtf((float)degi[i] + 1.0f);
}

// ---------------- exclusive scan (3 kernels) ----------------

__global__ __launch_bounds__(THREADS) void k_scan1(const int* __restrict__ degi,
                                                   int* __restrict__ rowptr,
                                                   int* __restrict__ bsum, int N) {
  __shared__ int s[THREADS];
  int i = blockIdx.x * THREADS + threadIdx.x;
  int v = (i < N) ? degi[i] : 0;
  s[threadIdx.x] = v;
  __syncthreads();
#pragma unroll
  for (int off = 1; off < THREADS; off <<= 1) {
    int t = (threadIdx.x >= off) ? s[threadIdx.x - off] : 0;
    __syncthreads();
    s[threadIdx.x] += t;
    __syncthreads();
  }
  if (i < N) rowptr[i] = s[threadIdx.x] - v;  // exclusive
  if (threadIdx.x == THREADS - 1) bsum[blockIdx.x] = s[THREADS - 1];
}

__global__ __launch_bounds__(512) void k_scan2(int* __restrict__ bsum, int nb) {
  __shared__ int s[512];
  int v = (threadIdx.x < nb) ? bsum[threadIdx.x] : 0;
  s[threadIdx.x] = v;
  __syncthreads();
#pragma unroll
  for (int off = 1; off < 512; off <<= 1) {
    int t = (threadIdx.x >= off) ? s[threadIdx.x - off] : 0;
    __syncthreads();
    s[threadIdx.x] += t;
    __syncthreads();
  }
  if (threadIdx.x < nb) bsum[threadIdx.x] = s[threadIdx.x] - v;  // exclusive
}

__global__ __launch_bounds__(THREADS) void k_scan3(int* __restrict__ rowptr,
                                                   const int* __restrict__ bsum,
                                                   int N, int E) {
  int i = blockIdx.x * THREADS + threadIdx.x;
  if (i < N) rowptr[i] += bsum[blockIdx.x];
  if (i == 0) rowptr[N] = E;
}

// ---------------- CSR placement: src index by dst (4B NT store) ----------------

__global__ __launch_bounds__(THREADS) void k_csr(const int* __restrict__ src,
                                                 const int* __restrict__ dst,
                                                 const int* __restrict__ rowptr,
                                                 int* __restrict__ cursor,
                                                 int* __restrict__ csrs, int E) {
  int e = blockIdx.x * THREADS + threadIdx.x;
  if (e >= E) return;
  int s = src[e];
  int d = dst[e];
  int pos = atomicAdd(&cursor[d], 1);
  __builtin_nontemporal_store(s, &csrs[rowptr[d] + pos]);
}

// ---------------- combined tail weights: Wc = W3@Wlin, bc = b3@Wlin + blin ----------------

__global__ __launch_bounds__(THREADS) void k_wcomb(const float* __restrict__ W3,
                                                   const float* __restrict__ Wl,
                                                   const float* __restrict__ b3,
                                                   const float* __restrict__ bl,
                                                   float* __restrict__ Wc,
                                                   float* __restrict__ bc) {
  int idx = blockIdx.x * THREADS + threadIdx.x;
  if (idx < 1024) {
    int k = idx >> 3, o = idx & 7;
    float a = 0.f;
#pragma unroll 8
    for (int j = 0; j < 128; ++j) a = fmaf(W3[k * 128 + j], Wl[j * 8 + o], a);
    Wc[idx] = a;
  }
  if (idx < 8) {
    float a = bl[idx];
    for (int j = 0; j < 128; ++j) a = fmaf(b3[j], Wl[j * 8 + idx], a);
    bc[idx] = a;
  }
}

// ---------------- loaders / stores ----------------

__device__ inline float4 ldrow4(const float* __restrict__ p) {
  return *(const float4*)p;
}

__device__ inline float4 ldrow4(const __half* __restrict__ p) {
  float2 raw = *(const float2*)p;  // 4 halves
  const __half2* h = (const __half2*)&raw;
  float2 a = __half22float2(h[0]);
  float2 b = __half22float2(h[1]);
  return make_float4(a.x, a.y, b.x, b.y);
}

struct f8 { float v[8]; };

__device__ inline f8 ld_h8(const __half* __restrict__ p) {
  float4 raw = *(const float4*)p;  // 8 halves, 16 B
  const __half2* h = (const __half2*)&raw;
  float2 a = __half22float2(h[0]);
  float2 b = __half22float2(h[1]);
  float2 c = __half22float2(h[2]);
  float2 d = __half22float2(h[3]);
  f8 o;
  o.v[0] = a.x; o.v[1] = a.y; o.v[2] = b.x; o.v[3] = b.y;
  o.v[4] = c.x; o.v[5] = c.y; o.v[6] = d.x; o.v[7] = d.y;
  return o;
}

// fp16 pack + non-temporal 8 B store
__device__ inline void st_nt_h4(__half* __restrict__ p, float x, float y,
                                float z, float w) {
  union {
    __half2 h2[2];
    unsigned long long u;
  } cv;
  cv.h2[0] = __floats2half2_rn(x, y);
  cv.h2[1] = __floats2half2_rn(z, w);
  __builtin_nontemporal_store(cv.u, (unsigned long long*)p);
}

// ---------------- GEMM: H16[M,128] = fp16(X[M,128] @ W[128,128]) ----------------

template <typename T>
__global__ __launch_bounds__(THREADS) void k_gemm128(const T* __restrict__ X,
                                                     const float* __restrict__ W,
                                                     __half* __restrict__ H16, int M) {
  __shared__ float4 sW[128 * 32];  // [k][colgroup] : W[k][c0..c0+3]
  const int t = threadIdx.x;
#pragma unroll
  for (int i = 0; i < 16; ++i) sW[t + i * 256] = ((const float4*)W)[t + i * 256];
  __syncthreads();

  const int tx = t & 31;
  const int ty = t >> 5;
  const int r0 = blockIdx.x * 64 + ty * 8;

  const T* xp[8];
#pragma unroll
  for (int i = 0; i < 8; ++i) {
    int r = r0 + i;
    if (r >= M) r = M - 1;
    xp[i] = X + (size_t)r * 128;
  }

  float4 acc[8];
#pragma unroll
  for (int i = 0; i < 8; ++i) acc[i] = make_float4(0.f, 0.f, 0.f, 0.f);

#pragma unroll 2
  for (int k = 0; k < 128; k += 4) {
    float4 xv[8];
#pragma unroll
    for (int i = 0; i < 8; ++i) xv[i] = ldrow4(xp[i] + k);
#pragma unroll
    for (int kk = 0; kk < 4; ++kk) {
      float4 w = sW[(k + kk) * 32 + tx];
#pragma unroll
      for (int i = 0; i < 8; ++i) {
        float xs = (kk == 0) ? xv[i].x : (kk == 1) ? xv[i].y : (kk == 2) ? xv[i].z : xv[i].w;
        acc[i].x = fmaf(xs, w.x, acc[i].x);
        acc[i].y = fmaf(xs, w.y, acc[i].y);
        acc[i].z = fmaf(xs, w.z, acc[i].z);
        acc[i].w = fmaf(xs, w.w, acc[i].w);
      }
    }
  }

#pragma unroll
  for (int i = 0; i < 8; ++i) {
    int r = r0 + i;
    if (r < M)
      st_nt_h4(H16 + (size_t)r * 128 + tx * 4, acc[i].x, acc[i].y, acc[i].z, acc[i].w);
  }
}

// ---------------- small GEMM: P3[M,8] = fp32(B16[M,128] @ Wc[128,8]) ----------------

__global__ __launch_bounds__(THREADS) void k_gemm8(const __half* __restrict__ B16,
                                                   const float* __restrict__ Wc,
                                                   float* __restrict__ P3, int M) {
  __shared__ float sWc[1024];
#pragma unroll
  for (int i = 0; i < 4; ++i) sWc[threadIdx.x + i * 256] = Wc[threadIdx.x + i * 256];
  __syncthreads();

  int i = blockIdx.x * THREADS + threadIdx.x;
  if (i >= M) return;

  float acc[8];
#pragma unroll
  for (int o = 0; o < 8; ++o) acc[o] = 0.f;

  const __half* row = B16 + (size_t)i * 128;
#pragma unroll 4
  for (int k = 0; k < 128; k += 8) {
    f8 x = ld_h8(row + k);
#pragma unroll
    for (int u = 0; u < 8; ++u) {
      const float* wr = &sWc[(k + u) * 8];
#pragma unroll
      for (int o = 0; o < 8; ++o) acc[o] = fmaf(x.v[u], wr[o], acc[o]);
    }
  }
  float4* out = (float4*)(P3 + (size_t)i * 8);
  out[0] = make_float4(acc[0], acc[1], acc[2], acc[3]);
  out[1] = make_float4(acc[4], acc[5], acc[6], acc[7]);
}

// ---------------- gather: B16[i] = fp16(relu(sum_in w*H16[src] + dinv_i^2*H16[i] + bias)) ----------------
// 32 lanes per dst node, 8 B per lane; unroll 4; w recomputed from dinv.

__global__ __launch_bounds__(THREADS) void k_gather(const __half* __restrict__ H16,
                                                    const int* __restrict__ rowptr,
                                                    const int* __restrict__ csrs,
                                                    const float* __restrict__ dinv,
                                                    const float* __restrict__ bias,
                                                    __half* __restrict__ B16, int N) {
  int gid = blockIdx.x * THREADS + threadIdx.x;
  int i = gid >> 5;
  int lane = gid & 31;
  if (i >= N) return;
  int beg = rowptr[i];
  int end = rowptr[i + 1];
  const float di = dinv[i];

  float4 acc = make_float4(0.f, 0.f, 0.f, 0.f);
  int k = beg;
  for (; k + 3 < end; k += 4) {
    int s0 = csrs[k],     s1 = csrs[k + 1];
    int s2 = csrs[k + 2], s3 = csrs[k + 3];
    float4 h0 = ldrow4(H16 + (size_t)s0 * 128 + lane * 4);
    float4 h1 = ldrow4(H16 + (size_t)s1 * 128 + lane * 4);
    float4 h2 = ldrow4(H16 + (size_t)s2 * 128 + lane * 4);
    float4 h3 = ldrow4(H16 + (size_t)s3 * 128 + lane * 4);
    float w0 = dinv[s0] * di, w1 = dinv[s1] * di;
    float w2 = dinv[s2] * di, w3 = dinv[s3] * di;
    acc.x = fmaf(w0, h0.x, acc.x); acc.y = fmaf(w0, h0.y, acc.y);
    acc.z = fmaf(w0, h0.z, acc.z); acc.w = fmaf(w0, h0.w, acc.w);
    acc.x = fmaf(w1, h1.x, acc.x); acc.y = fmaf(w1, h1.y, acc.y);
    acc.z = fmaf(w1, h1.z, acc.z); acc.w = fmaf(w1, h1.w, acc.w);
    acc.x = fmaf(w2, h2.x, acc.x); acc.y = fmaf(w2, h2.y, acc.y);
    acc.z = fmaf(w2, h2.z, acc.z); acc.w = fmaf(w2, h2.w, acc.w);
    acc.x = fmaf(w3, h3.x, acc.x); acc.y = fmaf(w3, h3.y, acc.y);
    acc.z = fmaf(w3, h3.z, acc.z); acc.w = fmaf(w3, h3.w, acc.w);
  }
  for (; k < end; ++k) {
    int s0 = csrs[k];
    float w0 = dinv[s0] * di;
    float4 h0 = ldrow4(H16 + (size_t)s0 * 128 + lane * 4);
    acc.x = fmaf(w0, h0.x, acc.x); acc.y = fmaf(w0, h0.y, acc.y);
    acc.z = fmaf(w0, h0.z, acc.z); acc.w = fmaf(w0, h0.w, acc.w);
  }

  float ns = di * di;
  float4 hs = ldrow4(H16 + (size_t)i * 128 + lane * 4);
  float4 bb = *(const float4*)(bias + lane * 4);
  float4 v;
  v.x = fmaxf(fmaf(hs.x, ns, acc.x) + bb.x, 0.f);
  v.y = fmaxf(fmaf(hs.y, ns, acc.y) + bb.y, 0.f);
  v.z = fmaxf(fmaf(hs.z, ns, acc.z) + bb.z, 0.f);
  v.w = fmaxf(fmaf(hs.w, ns, acc.w) + bb.w, 0.f);
  st_nt_h4(B16 + (size_t)i * 128 + lane * 4, v.x, v.y, v.z, v.w);
}

// ---------------- layer-3 gather+pool: pooled[batch[i], l] += (A-row_i . P3)[l] ----------------

__global__ __launch_bounds__(THREADS) void k_gather_pool(const float* __restrict__ P3,
                                                         const int* __restrict__ rowptr,
                                                         const int* __restrict__ csrs,
                                                         const float* __restrict__ dinv,
                                                         const int* __restrict__ batch,
                                                         float* __restrict__ pooled,
                                                         int N) {
  int gid = blockIdx.x * THREADS + threadIdx.x;
  int i = gid >> 3;
  int lane = gid & 7;
  if (i >= N) return;
  int beg = rowptr[i];
  int end = rowptr[i + 1];
  const float di = dinv[i];

  float acc = 0.f;
  int k = beg;
  for (; k + 1 < end; k += 2) {
    int sa = csrs[k], sb = csrs[k + 1];
    float pa = P3[(size_t)sa * 8 + lane];
    float pb = P3[(size_t)sb * 8 + lane];
    acc = fmaf(dinv[sa] * di, pa, acc);
    acc = fmaf(dinv[sb] * di, pb, acc);
  }
  if (k < end) {
    int sa = csrs[k];
    acc = fmaf(dinv[sa] * di, P3[(size_t)sa * 8 + lane], acc);
  }

  acc = fmaf(di * di, P3[(size_t)i * 8 + lane], acc);

  atomicAdd(&pooled[(size_t)batch[i] * 8 + lane], acc);
}

// ---------------- head: out[g,o] = pooled[g,o]/max(cnt,1) + bc[o] ----------------

__global__ __launch_bounds__(THREADS) void k_head(const float* __restrict__ pooled,
                                                  const float* __restrict__ cnts,
                                                  const float* __restrict__ bc,
                                                  float* __restrict__ out, int G) {
  int gid = blockIdx.x * THREADS + threadIdx.x;
  int g = gid >> 3;
  int o = gid & 7;
  if (g >= G) return;
  out[g * 8 + o] = pooled[g * 8 + o] / fmaxf(cnts[g], 1.0f) + bc[o];
}

// ---------------- launch ----------------

extern "C" void kernel_launch(void* const* d_in, const int* in_sizes, int n_in,
                              void* d_out, int out_size, void* d_ws, size_t ws_size,
                              hipStream_t stream) {
  const float* x     = (const float*)d_in[0];
  const int*   ei    = (const int*)d_in[1];
  const int*   batch = (const int*)d_in[3];
  const float* W1 = (const float*)d_in[4];
  const float* b1 = (const float*)d_in[5];
  const float* W2 = (const float*)d_in[6];
  const float* b2 = (const float*)d_in[7];
  const float* W3 = (const float*)d_in[8];
  const float* b3 = (const float*)d_in[9];
  const float* Wl = (const float*)d_in[10];
  const float* bl = (const float*)d_in[11];
  float* out = (float*)d_out;

  const int N = in_sizes[0] / 128;
  const int E = in_sizes[1] / 2;
  const int G = out_size / 8;
  const int* srcp = ei;
  const int* dstp = ei + E;

  char* ws = (char*)d_ws;
  __half* H16 = (__half*)ws;                       // [N,128] fp16 GEMM output
  __half* B16 = H16 + (size_t)N * 128;             // [N,128] fp16 activations
  float*  P3  = (float*)(B16 + (size_t)N * 128);   // [N,8] fp32 tail features
  // zeroed region: degi, cursor, pooled (contiguous)
  int*   degi   = (int*)(P3 + (size_t)N * 8);      // N
  int*   cursor = degi + N;                        // N
  float* pooled = (float*)(cursor + N);            // G*8
  // non-zeroed scratch
  float* cnts    = pooled + (size_t)G * 8;         // G (binary-search fill)
  float* dinv    = cnts + G;                       // N
  float* Wc      = dinv + N;                       // 1024
  float* bc      = Wc + 1024;                      // 8
  int*   rowptr  = (int*)(bc + 8);                 // N+1
  int*   bsum    = rowptr + N + 1;                 // scan partials (<=2048)
  int*   csrs    = bsum + 2048;                    // E src indices (4B records)

  const size_t zero_bytes = ((size_t)2 * N + (size_t)G * 8) * sizeof(float);
  (void)hipMemsetAsync(degi, 0, zero_bytes, stream);

  const int nbE = (E + THREADS - 1) / THREADS;
  const int nbN = (N + THREADS - 1) / THREADS;

  // ---- CSR build + tail-weight fold (once per call) ----
  k_deg<<<nbE, THREADS, 0, stream>>>(dstp, degi, E);
  k_cntbs<<<(G + THREADS - 1) / THREADS, THREADS, 0, stream>>>(batch, cnts, N, G);
  k_rsq<<<nbN, THREADS, 0, stream>>>(degi, dinv, N);
  k_scan1<<<nbN, THREADS, 0, stream>>>(degi, rowptr, bsum, N);
  k_scan2<<<1, 512, 0, stream>>>(bsum, nbN);
  k_scan3<<<nbN, THREADS, 0, stream>>>(rowptr, bsum, N, E);
  k_csr<<<nbE, THREADS, 0, stream>>>(srcp, dstp, rowptr, cursor, csrs, E);
  k_wcomb<<<4, THREADS, 0, stream>>>(W3, Wl, b3, bl, Wc, bc);

  const int gemm_blocks = (N + 63) / 64;
  const int gat_blocks = (int)(((long long)N * 32 + THREADS - 1) / THREADS);
  const int gp_blocks = (int)(((long long)N * 8 + THREADS - 1) / THREADS);

  // ---- layer 1 ----
  k_gemm128<float><<<gemm_blocks, THREADS, 0, stream>>>(x, W1, H16, N);
  k_gather<<<gat_blocks, THREADS, 0, stream>>>(H16, rowptr, csrs, dinv, b1, B16, N);
  // ---- layer 2 ----
  k_gemm128<__half><<<gemm_blocks, THREADS, 0, stream>>>(B16, W2, H16, N);
  k_gather<<<gat_blocks, THREADS, 0, stream>>>(H16, rowptr, csrs, dinv, b2, B16, N);
  // ---- layer 3 folded: P3 = B2 @ (W3@Wlin); gather+pool in 8-dim space ----
  k_gemm8<<<nbN, THREADS, 0, stream>>>(B16, Wc, P3, N);
  k_gather_pool<<<gp_blocks, THREADS, 0, stream>>>(P3, rowptr, csrs, dinv, batch, pooled, N);

  // ---- head ----
  k_head<<<(G * 8 + THREADS - 1) / THREADS, THREADS, 0, stream>>>(pooled, cnts, bc, out, G);
}

// Round 19
// 499.368 us; speedup vs baseline: 1.0877x; 1.0877x over previous
//
#include <hip/hip_runtime.h>
#include <hip/hip_fp16.h>

// GCN: 3x (h = X@W; agg = CSR-gather(norm_e * h[src]) + norm_self*h + b; relu)
// then mean-pool by graph id and a 128x8 linear head.
// R1: scatter->gather. R3: fp16 payload. R8: fp16 B + NT stores.
// R12: tail fold (layer-3 gather in 8-dim space). R13: 8-lane gather_pool.
// R14/R16: binary-search counts; NT csr scatter. 510-512 us BEST.
// R15 (reverted): bucket binning -> few-address atomic contention.
// R17 (reverted): 4B csr records -> WRITE unchanged (per-line-touch amp,
//      record-size-invariant), csr slower + gathers pay dinv reloads.
// R18: revert to R16. Component analysis says this decomposition is at its
//      floor: gathers at random-granule ceiling, csr at scatter dirty-line
//      floor (NT/binning/shrink all falsified), rest <30us each.

#define THREADS 256

// ---------------- degree(int) / dinv ----------------

__global__ __launch_bounds__(THREADS) void k_deg(const int* __restrict__ dst,
                                                 int* __restrict__ degi, int E) {
  int e = blockIdx.x * THREADS + threadIdx.x;
  if (e < E) atomicAdd(&degi[dst[e]], 1);
}

// counts via binary search over sorted batch (no atomics)
__global__ __launch_bounds__(THREADS) void k_cntbs(const int* __restrict__ batch,
                                                   float* __restrict__ cnts,
                                                   int N, int G) {
  int g = blockIdx.x * THREADS + threadIdx.x;
  if (g >= G) return;
  int lo = 0, hi = N;
  while (lo < hi) {
    int mid = (lo + hi) >> 1;
    if (batch[mid] < g) lo = mid + 1; else hi = mid;
  }
  int lb0 = lo;
  lo = 0; hi = N;
  while (lo < hi) {
    int mid = (lo + hi) >> 1;
    if (batch[mid] < g + 1) lo = mid + 1; else hi = mid;
  }
  cnts[g] = (float)(lo - lb0);
}

__global__ __launch_bounds__(THREADS) void k_rsq(const int* __restrict__ degi,
                                                 float* __restrict__ dinv, int N) {
  int i = blockIdx.x * THREADS + threadIdx.x;
  if (i < N) dinv[i] = rsqrtf((float)degi[i] + 1.0f);
}

// ---------------- exclusive scan (3 kernels) ----------------

__global__ __launch_bounds__(THREADS) void k_scan1(const int* __restrict__ degi,
                                                   int* __restrict__ rowptr,
                                                   int* __restrict__ bsum, int N) {
  __shared__ int s[THREADS];
  int i = blockIdx.x * THREADS + threadIdx.x;
  int v = (i < N) ? degi[i] : 0;
  s[threadIdx.x] = v;
  __syncthreads();
#pragma unroll
  for (int off = 1; off < THREADS; off <<= 1) {
    int t = (threadIdx.x >= off) ? s[threadIdx.x - off] : 0;
    __syncthreads();
    s[threadIdx.x] += t;
    __syncthreads();
  }
  if (i < N) rowptr[i] = s[threadIdx.x] - v;  // exclusive
  if (threadIdx.x == THREADS - 1) bsum[blockIdx.x] = s[THREADS - 1];
}

__global__ __launch_bounds__(512) void k_scan2(int* __restrict__ bsum, int nb) {
  __shared__ int s[512];
  int v = (threadIdx.x < nb) ? bsum[threadIdx.x] : 0;
  s[threadIdx.x] = v;
  __syncthreads();
#pragma unroll
  for (int off = 1; off < 512; off <<= 1) {
    int t = (threadIdx.x >= off) ? s[threadIdx.x - off] : 0;
    __syncthreads();
    s[threadIdx.x] += t;
    __syncthreads();
  }
  if (threadIdx.x < nb) bsum[threadIdx.x] = s[threadIdx.x] - v;  // exclusive
}

__global__ __launch_bounds__(THREADS) void k_scan3(int* __restrict__ rowptr,
                                                   const int* __restrict__ bsum,
                                                   int N, int E) {
  int i = blockIdx.x * THREADS + threadIdx.x;
  if (i < N) rowptr[i] += bsum[blockIdx.x];
  if (i == 0) rowptr[N] = E;
}

// ---------------- CSR placement: packed {src, w} records by dst (NT store) ----------------

__global__ __launch_bounds__(THREADS) void k_csr(const int* __restrict__ src,
                                                 const int* __restrict__ dst,
                                                 const int* __restrict__ rowptr,
                                                 int* __restrict__ cursor,
                                                 const float* __restrict__ dinv,
                                                 int2* __restrict__ rec, int E) {
  int e = blockIdx.x * THREADS + threadIdx.x;
  if (e >= E) return;
  int s = src[e];
  int d = dst[e];
  int pos = atomicAdd(&cursor[d], 1);
  int idx = rowptr[d] + pos;
  float w = dinv[s] * dinv[d];
  union {
    int2 v;
    unsigned long long u;
  } cv;
  cv.v = make_int2(s, __float_as_int(w));
  __builtin_nontemporal_store(cv.u, (unsigned long long*)&rec[idx]);
}

// ---------------- combined tail weights: Wc = W3@Wlin, bc = b3@Wlin + blin ----------------

__global__ __launch_bounds__(THREADS) void k_wcomb(const float* __restrict__ W3,
                                                   const float* __restrict__ Wl,
                                                   const float* __restrict__ b3,
                                                   const float* __restrict__ bl,
                                                   float* __restrict__ Wc,
                                                   float* __restrict__ bc) {
  int idx = blockIdx.x * THREADS + threadIdx.x;
  if (idx < 1024) {
    int k = idx >> 3, o = idx & 7;
    float a = 0.f;
#pragma unroll 8
    for (int j = 0; j < 128; ++j) a = fmaf(W3[k * 128 + j], Wl[j * 8 + o], a);
    Wc[idx] = a;
  }
  if (idx < 8) {
    float a = bl[idx];
    for (int j = 0; j < 128; ++j) a = fmaf(b3[j], Wl[j * 8 + idx], a);
    bc[idx] = a;
  }
}

// ---------------- loaders / stores ----------------

__device__ inline float4 ldrow4(const float* __restrict__ p) {
  return *(const float4*)p;
}

__device__ inline float4 ldrow4(const __half* __restrict__ p) {
  float2 raw = *(const float2*)p;  // 4 halves
  const __half2* h = (const __half2*)&raw;
  float2 a = __half22float2(h[0]);
  float2 b = __half22float2(h[1]);
  return make_float4(a.x, a.y, b.x, b.y);
}

struct f8 { float v[8]; };

__device__ inline f8 ld_h8(const __half* __restrict__ p) {
  float4 raw = *(const float4*)p;  // 8 halves, 16 B
  const __half2* h = (const __half2*)&raw;
  float2 a = __half22float2(h[0]);
  float2 b = __half22float2(h[1]);
  float2 c = __half22float2(h[2]);
  float2 d = __half22float2(h[3]);
  f8 o;
  o.v[0] = a.x; o.v[1] = a.y; o.v[2] = b.x; o.v[3] = b.y;
  o.v[4] = c.x; o.v[5] = c.y; o.v[6] = d.x; o.v[7] = d.y;
  return o;
}

// fp16 pack + non-temporal 8 B store
__device__ inline void st_nt_h4(__half* __restrict__ p, float x, float y,
                                float z, float w) {
  union {
    __half2 h2[2];
    unsigned long long u;
  } cv;
  cv.h2[0] = __floats2half2_rn(x, y);
  cv.h2[1] = __floats2half2_rn(z, w);
  __builtin_nontemporal_store(cv.u, (unsigned long long*)p);
}

// ---------------- GEMM: H16[M,128] = fp16(X[M,128] @ W[128,128]) ----------------

template <typename T>
__global__ __launch_bounds__(THREADS) void k_gemm128(const T* __restrict__ X,
                                                     const float* __restrict__ W,
                                                     __half* __restrict__ H16, int M) {
  __shared__ float4 sW[128 * 32];  // [k][colgroup] : W[k][c0..c0+3]
  const int t = threadIdx.x;
#pragma unroll
  for (int i = 0; i < 16; ++i) sW[t + i * 256] = ((const float4*)W)[t + i * 256];
  __syncthreads();

  const int tx = t & 31;
  const int ty = t >> 5;
  const int r0 = blockIdx.x * 64 + ty * 8;

  const T* xp[8];
#pragma unroll
  for (int i = 0; i < 8; ++i) {
    int r = r0 + i;
    if (r >= M) r = M - 1;
    xp[i] = X + (size_t)r * 128;
  }

  float4 acc[8];
#pragma unroll
  for (int i = 0; i < 8; ++i) acc[i] = make_float4(0.f, 0.f, 0.f, 0.f);

#pragma unroll 2
  for (int k = 0; k < 128; k += 4) {
    float4 xv[8];
#pragma unroll
    for (int i = 0; i < 8; ++i) xv[i] = ldrow4(xp[i] + k);
#pragma unroll
    for (int kk = 0; kk < 4; ++kk) {
      float4 w = sW[(k + kk) * 32 + tx];
#pragma unroll
      for (int i = 0; i < 8; ++i) {
        float xs = (kk == 0) ? xv[i].x : (kk == 1) ? xv[i].y : (kk == 2) ? xv[i].z : xv[i].w;
        acc[i].x = fmaf(xs, w.x, acc[i].x);
        acc[i].y = fmaf(xs, w.y, acc[i].y);
        acc[i].z = fmaf(xs, w.z, acc[i].z);
        acc[i].w = fmaf(xs, w.w, acc[i].w);
      }
    }
  }

#pragma unroll
  for (int i = 0; i < 8; ++i) {
    int r = r0 + i;
    if (r < M)
      st_nt_h4(H16 + (size_t)r * 128 + tx * 4, acc[i].x, acc[i].y, acc[i].z, acc[i].w);
  }
}

// ---------------- small GEMM: P3[M,8] = fp32(B16[M,128] @ Wc[128,8]) ----------------

__global__ __launch_bounds__(THREADS) void k_gemm8(const __half* __restrict__ B16,
                                                   const float* __restrict__ Wc,
                                                   float* __restrict__ P3, int M) {
  __shared__ float sWc[1024];
#pragma unroll
  for (int i = 0; i < 4; ++i) sWc[threadIdx.x + i * 256] = Wc[threadIdx.x + i * 256];
  __syncthreads();

  int i = blockIdx.x * THREADS + threadIdx.x;
  if (i >= M) return;

  float acc[8];
#pragma unroll
  for (int o = 0; o < 8; ++o) acc[o] = 0.f;

  const __half* row = B16 + (size_t)i * 128;
#pragma unroll 4
  for (int k = 0; k < 128; k += 8) {
    f8 x = ld_h8(row + k);
#pragma unroll
    for (int u = 0; u < 8; ++u) {
      const float* wr = &sWc[(k + u) * 8];
#pragma unroll
      for (int o = 0; o < 8; ++o) acc[o] = fmaf(x.v[u], wr[o], acc[o]);
    }
  }
  float4* out = (float4*)(P3 + (size_t)i * 8);
  out[0] = make_float4(acc[0], acc[1], acc[2], acc[3]);
  out[1] = make_float4(acc[4], acc[5], acc[6], acc[7]);
}

// ---------------- gather: B16[i] = fp16(relu(sum_in w*H16[src] + dinv_i^2*H16[i] + bias)) ----------------
// R8 proven shape: 32 lanes per dst node, 8 B per lane; unroll 4; NT store.

__global__ __launch_bounds__(THREADS) void k_gather(const __half* __restrict__ H16,
                                                    const int* __restrict__ rowptr,
                                                    const int2* __restrict__ rec,
                                                    const float* __restrict__ dinv,
                                                    const float* __restrict__ bias,
                                                    __half* __restrict__ B16, int N) {
  int gid = blockIdx.x * THREADS + threadIdx.x;
  int i = gid >> 5;
  int lane = gid & 31;
  if (i >= N) return;
  int beg = rowptr[i];
  int end = rowptr[i + 1];

  float4 acc = make_float4(0.f, 0.f, 0.f, 0.f);
  int k = beg;
  for (; k + 3 < end; k += 4) {
    int2 r0 = rec[k],     r1 = rec[k + 1];
    int2 r2 = rec[k + 2], r3 = rec[k + 3];
    float4 h0 = ldrow4(H16 + (size_t)r0.x * 128 + lane * 4);
    float4 h1 = ldrow4(H16 + (size_t)r1.x * 128 + lane * 4);
    float4 h2 = ldrow4(H16 + (size_t)r2.x * 128 + lane * 4);
    float4 h3 = ldrow4(H16 + (size_t)r3.x * 128 + lane * 4);
    float w0 = __int_as_float(r0.y), w1 = __int_as_float(r1.y);
    float w2 = __int_as_float(r2.y), w3 = __int_as_float(r3.y);
    acc.x = fmaf(w0, h0.x, acc.x); acc.y = fmaf(w0, h0.y, acc.y);
    acc.z = fmaf(w0, h0.z, acc.z); acc.w = fmaf(w0, h0.w, acc.w);
    acc.x = fmaf(w1, h1.x, acc.x); acc.y = fmaf(w1, h1.y, acc.y);
    acc.z = fmaf(w1, h1.z, acc.z); acc.w = fmaf(w1, h1.w, acc.w);
    acc.x = fmaf(w2, h2.x, acc.x); acc.y = fmaf(w2, h2.y, acc.y);
    acc.z = fmaf(w2, h2.z, acc.z); acc.w = fmaf(w2, h2.w, acc.w);
    acc.x = fmaf(w3, h3.x, acc.x); acc.y = fmaf(w3, h3.y, acc.y);
    acc.z = fmaf(w3, h3.z, acc.z); acc.w = fmaf(w3, h3.w, acc.w);
  }
  for (; k < end; ++k) {
    int2 r0 = rec[k];
    float w0 = __int_as_float(r0.y);
    float4 h0 = ldrow4(H16 + (size_t)r0.x * 128 + lane * 4);
    acc.x = fmaf(w0, h0.x, acc.x); acc.y = fmaf(w0, h0.y, acc.y);
    acc.z = fmaf(w0, h0.z, acc.z); acc.w = fmaf(w0, h0.w, acc.w);
  }

  float di = dinv[i];
  float ns = di * di;
  float4 hs = ldrow4(H16 + (size_t)i * 128 + lane * 4);
  float4 bb = *(const float4*)(bias + lane * 4);
  float4 v;
  v.x = fmaxf(fmaf(hs.x, ns, acc.x) + bb.x, 0.f);
  v.y = fmaxf(fmaf(hs.y, ns, acc.y) + bb.y, 0.f);
  v.z = fmaxf(fmaf(hs.z, ns, acc.z) + bb.z, 0.f);
  v.w = fmaxf(fmaf(hs.w, ns, acc.w) + bb.w, 0.f);
  st_nt_h4(B16 + (size_t)i * 128 + lane * 4, v.x, v.y, v.z, v.w);
}

// ---------------- layer-3 gather+pool: pooled[batch[i], l] += (A-row_i . P3)[l] ----------------

__global__ __launch_bounds__(THREADS) void k_gather_pool(const float* __restrict__ P3,
                                                         const int* __restrict__ rowptr,
                                                         const int2* __restrict__ rec,
                                                         const float* __restrict__ dinv,
                                                         const int* __restrict__ batch,
                                                         float* __restrict__ pooled,
                                                         int N) {
  int gid = blockIdx.x * THREADS + threadIdx.x;
  int i = gid >> 3;
  int lane = gid & 7;
  if (i >= N) return;
  int beg = rowptr[i];
  int end = rowptr[i + 1];

  float acc = 0.f;
  int k = beg;
  for (; k + 1 < end; k += 2) {
    int2 ra = rec[k], rb = rec[k + 1];
    float pa = P3[(size_t)ra.x * 8 + lane];
    float pb = P3[(size_t)rb.x * 8 + lane];
    acc = fmaf(__int_as_float(ra.y), pa, acc);
    acc = fmaf(__int_as_float(rb.y), pb, acc);
  }
  if (k < end) {
    int2 ra = rec[k];
    acc = fmaf(__int_as_float(ra.y), P3[(size_t)ra.x * 8 + lane], acc);
  }

  float dd = dinv[i];
  acc = fmaf(dd * dd, P3[(size_t)i * 8 + lane], acc);

  atomicAdd(&pooled[(size_t)batch[i] * 8 + lane], acc);
}

// ---------------- head: out[g,o] = pooled[g,o]/max(cnt,1) + bc[o] ----------------

__global__ __launch_bounds__(THREADS) void k_head(const float* __restrict__ pooled,
                                                  const float* __restrict__ cnts,
                                                  const float* __restrict__ bc,
                                                  float* __restrict__ out, int G) {
  int gid = blockIdx.x * THREADS + threadIdx.x;
  int g = gid >> 3;
  int o = gid & 7;
  if (g >= G) return;
  out[g * 8 + o] = pooled[g * 8 + o] / fmaxf(cnts[g], 1.0f) + bc[o];
}

// ---------------- launch ----------------

extern "C" void kernel_launch(void* const* d_in, const int* in_sizes, int n_in,
                              void* d_out, int out_size, void* d_ws, size_t ws_size,
                              hipStream_t stream) {
  const float* x     = (const float*)d_in[0];
  const int*   ei    = (const int*)d_in[1];
  const int*   batch = (const int*)d_in[3];
  const float* W1 = (const float*)d_in[4];
  const float* b1 = (const float*)d_in[5];
  const float* W2 = (const float*)d_in[6];
  const float* b2 = (const float*)d_in[7];
  const float* W3 = (const float*)d_in[8];
  const float* b3 = (const float*)d_in[9];
  const float* Wl = (const float*)d_in[10];
  const float* bl = (const float*)d_in[11];
  float* out = (float*)d_out;

  const int N = in_sizes[0] / 128;
  const int E = in_sizes[1] / 2;
  const int G = out_size / 8;
  const int* srcp = ei;
  const int* dstp = ei + E;

  char* ws = (char*)d_ws;
  __half* H16 = (__half*)ws;                       // [N,128] fp16 GEMM output
  __half* B16 = H16 + (size_t)N * 128;             // [N,128] fp16 activations
  float*  P3  = (float*)(B16 + (size_t)N * 128);   // [N,8] fp32 tail features
  // zeroed region: degi, cursor, pooled (contiguous)
  int*   degi   = (int*)(P3 + (size_t)N * 8);      // N
  int*   cursor = degi + N;                        // N
  float* pooled = (float*)(cursor + N);            // G*8
  // non-zeroed scratch
  float* cnts    = pooled + (size_t)G * 8;         // G (binary-search fill)
  float* dinv    = cnts + G;                       // N
  float* Wc      = dinv + N;                       // 1024
  float* bc      = Wc + 1024;                      // 8
  int*   rowptr  = (int*)(bc + 8);                 // N+1
  int*   bsum    = rowptr + N + 1;                 // scan partials (<=2048)
  int2*  rec     = (int2*)(bsum + 2048);           // E packed records

  const size_t zero_bytes = ((size_t)2 * N + (size_t)G * 8) * sizeof(float);
  (void)hipMemsetAsync(degi, 0, zero_bytes, stream);

  const int nbE = (E + THREADS - 1) / THREADS;
  const int nbN = (N + THREADS - 1) / THREADS;

  // ---- CSR build + tail-weight fold (once per call) ----
  k_deg<<<nbE, THREADS, 0, stream>>>(dstp, degi, E);
  k_cntbs<<<(G + THREADS - 1) / THREADS, THREADS, 0, stream>>>(batch, cnts, N, G);
  k_rsq<<<nbN, THREADS, 0, stream>>>(degi, dinv, N);
  k_scan1<<<nbN, THREADS, 0, stream>>>(degi, rowptr, bsum, N);
  k_scan2<<<1, 512, 0, stream>>>(bsum, nbN);
  k_scan3<<<nbN, THREADS, 0, stream>>>(rowptr, bsum, N, E);
  k_csr<<<nbE, THREADS, 0, stream>>>(srcp, dstp, rowptr, cursor, dinv, rec, E);
  k_wcomb<<<4, THREADS, 0, stream>>>(W3, Wl, b3, bl, Wc, bc);

  const int gemm_blocks = (N + 63) / 64;
  const int gat_blocks = (int)(((long long)N * 32 + THREADS - 1) / THREADS);
  const int gp_blocks = (int)(((long long)N * 8 + THREADS - 1) / THREADS);

  // ---- layer 1 ----
  k_gemm128<float><<<gemm_blocks, THREADS, 0, stream>>>(x, W1, H16, N);
  k_gather<<<gat_blocks, THREADS, 0, stream>>>(H16, rowptr, rec, dinv, b1, B16, N);
  // ---- layer 2 ----
  k_gemm128<__half><<<gemm_blocks, THREADS, 0, stream>>>(B16, W2, H16, N);
  k_gather<<<gat_blocks, THREADS, 0, stream>>>(H16, rowptr, rec, dinv, b2, B16, N);
  // ---- layer 3 folded: P3 = B2 @ (W3@Wlin); gather+pool in 8-dim space ----
  k_gemm8<<<nbN, THREADS, 0, stream>>>(B16, Wc, P3, N);
  k_gather_pool<<<gp_blocks, THREADS, 0, stream>>>(P3, rowptr, rec, dinv, batch, pooled, N);

  // ---- head ----
  k_head<<<(G * 8 + THREADS - 1) / THREADS, THREADS, 0, stream>>>(pooled, cnts, bc, out, G);
}